// Round 5
// baseline (152.718 us; speedup 1.0000x reference)
//
#include <hip/hip_runtime.h>
#include <hip/hip_bf16.h>
#include <cstddef>

#define T_TOK 1024
#define D_DIM 1024
#define H_DIM 512
#define E_EXP 8
#define P_CAP 2560          // max padded pairs @64-align: 2048 + 8*63 = 2552 -> 2560
#define MAX_MT 40           // 64-row m-tiles
#define LDA 72              // shorts per LDS row: 64 data + 8 pad (144B, 16B-aligned)
#define NK1 16              // gemm1 K-steps: 1024/64
#define NK2 8               // gemm2 K-steps: 512/64

typedef __attribute__((ext_vector_type(4)))  float    float4_t;
typedef __attribute__((ext_vector_type(16))) float    f32x16;
typedef __attribute__((ext_vector_type(8)))  short    short8_t;
typedef __attribute__((ext_vector_type(4)))  unsigned uint4_t;

__device__ __forceinline__ short f2bf(float f) {
  union { float f; unsigned u; } v; v.f = f;
  unsigned u = v.u;
  u += 0x7FFFu + ((u >> 16) & 1u);
  return (short)(u >> 16);
}

// packed fp32x2 -> bf16x2; low short = a, high = b
__device__ __forceinline__ unsigned pkbf(float a, float b) {
  union { __hip_bfloat162 h; unsigned u; } v;
  v.h = __float22bfloat162_rn(make_float2(a, b));
  return v.u;
}

// ---- prep: flat 1-D grid of 3584 real work units (no idle blocks):
//   u <  2048 : w1/w3 transpose 64x64 tiles (16 z * 16 kt * 8 nt)
//   u <  3072 : w2 transpose tiles (8 e * 8 kt * 16 nt)
//   u <  3328 : router, 4 tokens per unit
//   u <  3584 : out-zero, 16 KB per unit
__global__ __launch_bounds__(256) void prep_kernel(
    const float* __restrict__ w1, const float* __restrict__ w3,
    const float* __restrict__ w2, const float* __restrict__ x,
    const float* __restrict__ gw, short* __restrict__ w13t,
    short* __restrict__ w2t, int* __restrict__ idx2,
    float* __restrict__ scale2, float* __restrict__ out) {
  __shared__ float tile[64][69];           // odd stride keeps transpose <=2-way
  const int u = blockIdx.x;
  const int tid = threadIdx.x;

  if (u < 3072) {
    const float* src; short* dst; int N, ldd, row_off, k0, n0;
    if (u < 2048) {
      int z = u >> 7, rem = u & 127;
      int kt = rem & 15, nt = rem >> 4;    // 16 kt x 8 nt
      int which = z >> 3, e = z & 7;
      src = (which ? w3 : w1) + (size_t)e * D_DIM * H_DIM;
      dst = w13t + (size_t)e * D_DIM * (2 * H_DIM);
      N = H_DIM; ldd = D_DIM; row_off = which ? H_DIM : 0;
      k0 = kt * 64; n0 = nt * 64;
    } else {
      int v = u - 2048;
      int e = v >> 7, rem = v & 127;
      int kt = rem & 7, nt = rem >> 3;     // 8 kt x 16 nt
      src = w2 + (size_t)e * H_DIM * D_DIM;
      dst = w2t + (size_t)e * D_DIM * H_DIM;
      N = D_DIM; ldd = H_DIM; row_off = 0;
      k0 = kt * 64; n0 = nt * 64;
    }
    const int kr = tid >> 4, nc = (tid & 15) * 4;
    #pragma unroll
    for (int p = 0; p < 4; ++p) {
      int k = p * 16 + kr;
      float4_t v = *(const float4_t*)(src + (size_t)(k0 + k) * N + n0 + nc);
      tile[k][nc]     = v[0];
      tile[k][nc + 1] = v[1];
      tile[k][nc + 2] = v[2];
      tile[k][nc + 3] = v[3];
    }
    __syncthreads();
    const int r8 = tid >> 3, c8 = tid & 7;
    #pragma unroll
    for (int p = 0; p < 2; ++p) {
      int row = p * 32 + r8;
      uint4_t uu;
      #pragma unroll
      for (int jj = 0; jj < 4; ++jj)
        uu[jj] = pkbf(tile[c8 * 8 + 2 * jj][row], tile[c8 * 8 + 2 * jj + 1][row]);
      *(uint4_t*)(dst + (size_t)(row_off + n0 + row) * ldd + k0 + c8 * 8) = uu;
    }
    return;
  }

  if (u >= 3328) {                          // out zero: 256 units x 16KB
    int v = u - 3328;
    float4_t z4 = {0.f, 0.f, 0.f, 0.f};
    float4_t* o = (float4_t*)(out + (size_t)v * 4096);
    #pragma unroll
    for (int i = 0; i < 4; ++i) o[i * 256 + tid] = z4;
    return;
  }

  // router: 4 tokens per unit (one wave each)
  const int wid  = tid >> 6;
  const int lane = tid & 63;
  const int t = (u - 3072) * 4 + wid;
  const float* xr = x + (size_t)t * D_DIM;
  float acc[E_EXP];
  #pragma unroll
  for (int e = 0; e < E_EXP; ++e) acc[e] = 0.f;
  for (int d = lane; d < D_DIM; d += 64) {
    float xv = xr[d];
    float4_t g0 = *(const float4_t*)(gw + d * E_EXP);
    float4_t g1 = *(const float4_t*)(gw + d * E_EXP + 4);
    acc[0] += xv * g0[0]; acc[1] += xv * g0[1];
    acc[2] += xv * g0[2]; acc[3] += xv * g0[3];
    acc[4] += xv * g1[0]; acc[5] += xv * g1[1];
    acc[6] += xv * g1[2]; acc[7] += xv * g1[3];
  }
  #pragma unroll
  for (int off = 32; off >= 1; off >>= 1) {
    #pragma unroll
    for (int e = 0; e < E_EXP; ++e) acc[e] += __shfl_down(acc[e], off, 64);
  }
  if (lane == 0) {
    float m = acc[0];
    #pragma unroll
    for (int e = 1; e < E_EXP; ++e) m = fmaxf(m, acc[e]);
    float p[E_EXP]; float s = 0.f;
    #pragma unroll
    for (int e = 0; e < E_EXP; ++e) { p[e] = __expf(acc[e] - m); s += p[e]; }
    float inv = 1.f / s;
    #pragma unroll
    for (int e = 0; e < E_EXP; ++e) p[e] *= inv;
    int i1 = 0;
    #pragma unroll
    for (int e = 1; e < E_EXP; ++e) if (p[e] > p[i1]) i1 = e;  // jax low-index tiebreak
    int i2 = (i1 == 0) ? 1 : 0;
    #pragma unroll
    for (int e = 0; e < E_EXP; ++e) {
      if (e == i1 || e == i2) continue;
      if (p[e] > p[i2]) i2 = e;
    }
    idx2[2 * t]     = i1;  scale2[2 * t]     = p[i1];
    idx2[2 * t + 1] = i2;  scale2[2 * t + 1] = p[i2];
  }
}

// ---- scan/assign: ballot-based, atomic-free (old LDS-atomic version
// serialized ~64-way on 8 counters, ~6-8 us with the whole GPU idle).
// Slot of (t, s) = base[e] + prefix over (chunk, wave, slot0-first, lane).
__global__ __launch_bounds__(256) void scan_kernel(
    const int* __restrict__ idx2, const float* __restrict__ scale2,
    int* __restrict__ pair_tok, float* __restrict__ pair_scale,
    int* __restrict__ meta) {
  __shared__ int wcnt[16][E_EXP];          // [chunk*4+wave][expert]
  __shared__ int woff[16][E_EXP];
  __shared__ int sbase[E_EXP], stot[E_EXP];
  const int tid = threadIdx.x;
  const int lane = tid & 63, wv = tid >> 6;
  const unsigned long long lt = (1ull << lane) - 1ull;

  for (int p = tid; p < P_CAP; p += 256) { pair_tok[p] = -1; pair_scale[p] = 0.f; }

  int e0[4], e1[4];
  #pragma unroll
  for (int c = 0; c < 4; ++c) {
    int t = c * 256 + wv * 64 + lane;
    e0[c] = idx2[2 * t];
    e1[c] = idx2[2 * t + 1];
  }
  #pragma unroll
  for (int c = 0; c < 4; ++c) {
    #pragma unroll
    for (int e = 0; e < E_EXP; ++e) {
      unsigned long long m0 = __ballot(e0[c] == e);
      unsigned long long m1 = __ballot(e1[c] == e);
      if (lane == 0) wcnt[c * 4 + wv][e] = __popcll(m0) + __popcll(m1);
    }
  }
  __syncthreads();
  if (tid < E_EXP) {
    int s = 0;
    for (int r = 0; r < 16; ++r) s += wcnt[r][tid];
    stot[tid] = s;
  }
  __syncthreads();
  if (tid == 0) {
    int b = 0, g = 0;
    for (int e = 0; e < E_EXP; ++e) {
      sbase[e] = b;
      int al = (stot[e] + 63) & ~63;       // 64-row tiles
      for (int j = 0; j < al; j += 64) { meta[1 + g] = e; meta[81 + g] = b + j; ++g; }
      b += al;
    }
    meta[0] = g;                           // n_mtiles (<= 40)
  }
  __syncthreads();
  if (tid < E_EXP) {
    int run = sbase[tid];
    for (int r = 0; r < 16; ++r) { woff[r][tid] = run; run += wcnt[r][tid]; }
  }
  __syncthreads();
  #pragma unroll
  for (int c = 0; c < 4; ++c) {
    int t = c * 256 + wv * 64 + lane;
    int a0 = e0[c], a1 = e1[c];
    #pragma unroll
    for (int e = 0; e < E_EXP; ++e) {
      unsigned long long m0 = __ballot(a0 == e);
      unsigned long long m1 = __ballot(a1 == e);
      int base = woff[c * 4 + wv][e];
      if (a0 == e) {
        int pos = base + (int)__popcll(m0 & lt);
        pair_tok[pos] = t; pair_scale[pos] = scale2[2 * t];
      }
      if (a1 == e) {
        int pos = base + (int)__popcll(m0) + (int)__popcll(m1 & lt);
        pair_tok[pos] = t; pair_scale[pos] = scale2[2 * t + 1];
      }
    }
  }
}

// ------- gemm1: h = silu((s*x)@w1e) * ((s*x)@w3e); block 64m x 64n ---------
// A gather+scale+convert fused into staging. 32x32x16 MFMA; A/B frag
// row=lane&31, k=(lane>>5)*8+j; C/D col=lane&31,
// row=(reg&3)+8*(reg>>2)+4*(lane>>5)  [m74/m101 verified].
__global__ __launch_bounds__(256, 2) void gemm1_kernel(
    const float* __restrict__ x, const short* __restrict__ w13t,
    const int* __restrict__ pair_tok, const float* __restrict__ pair_scale,
    const int* __restrict__ meta, short* __restrict__ h) {
  __shared__ short As[2][64 * LDA];    // 18.4 KB
  __shared__ short B1s[2][64 * LDA];   // 18.4 KB
  __shared__ short B3s[2][64 * LDA];   // 18.4 KB -> 55.3 KB total
  const int mt = blockIdx.y;
  if (mt >= meta[0]) return;
  const int e    = meta[1 + mt];
  const int row0 = meta[81 + mt];
  const int n0   = blockIdx.x * 64;
  const int tid = threadIdx.x, lane = tid & 63, wid = tid >> 6;
  const int wm = wid >> 1, wn = wid & 1;        // 2x2 waves, each 32m x 32n
  const int l31 = lane & 31, lh = lane >> 5;
  const short* bsrc = w13t + (size_t)e * D_DIM * (2 * H_DIM);

  const int sr = tid >> 3, su = (tid & 7) * 8;
  const size_t st32 = (size_t)32 * D_DIM;
  const int   tok0 = pair_tok[row0 + sr];
  const int   tok1 = pair_tok[row0 + sr + 32];
  const float sc0  = pair_scale[row0 + sr];       // 0 for pad rows -> zeros
  const float sc1  = pair_scale[row0 + sr + 32];
  const float* xr0 = x + (size_t)(tok0 < 0 ? 0 : tok0) * D_DIM + su;
  const float* xr1 = x + (size_t)(tok1 < 0 ? 0 : tok1) * D_DIM + su;
  const short* ap1 = bsrc + (size_t)(n0 + sr) * D_DIM + su;
  const short* ap3 = bsrc + (size_t)(H_DIM + n0 + sr) * D_DIM + su;

  f32x16 acc1, acc3;
  #pragma unroll
  for (int i = 0; i < 16; ++i) { acc1[i] = 0.f; acc3[i] = 0.f; }

  {                                            // prologue: stage tile 0
    float4_t v0 = *(const float4_t*)(xr0);
    float4_t v1 = *(const float4_t*)(xr0 + 4);
    float4_t w0 = *(const float4_t*)(xr1);
    float4_t w1v = *(const float4_t*)(xr1 + 4);
    uint4_t a0 = {pkbf(v0[0] * sc0, v0[1] * sc0), pkbf(v0[2] * sc0, v0[3] * sc0),
                  pkbf(v1[0] * sc0, v1[1] * sc0), pkbf(v1[2] * sc0, v1[3] * sc0)};
    uint4_t a1 = {pkbf(w0[0] * sc1, w0[1] * sc1), pkbf(w0[2] * sc1, w0[3] * sc1),
                  pkbf(w1v[0] * sc1, w1v[1] * sc1), pkbf(w1v[2] * sc1, w1v[3] * sc1)};
    uint4_t p0 = *(const uint4_t*)ap1;
    uint4_t p1 = *(const uint4_t*)(ap1 + st32);
    uint4_t q0 = *(const uint4_t*)ap3;
    uint4_t q1 = *(const uint4_t*)(ap3 + st32);
    *(uint4_t*)&As[0][sr * LDA + su]         = a0;
    *(uint4_t*)&As[0][(sr + 32) * LDA + su]  = a1;
    *(uint4_t*)&B1s[0][sr * LDA + su]        = p0;
    *(uint4_t*)&B1s[0][(sr + 32) * LDA + su] = p1;
    *(uint4_t*)&B3s[0][sr * LDA + su]        = q0;
    *(uint4_t*)&B3s[0][(sr + 32) * LDA + su] = q1;
  }

  for (int t = 0; t < NK1 - 1; ++t) {
    __syncthreads();
    const int cur = t & 1, nxt = cur ^ 1;
    const int ko = (t + 1) * 64;
    float4_t v0 = *(const float4_t*)(xr0 + ko);
    float4_t v1 = *(const float4_t*)(xr0 + ko + 4);
    float4_t w0 = *(const float4_t*)(xr1 + ko);
    float4_t w1v = *(const float4_t*)(xr1 + ko + 4);
    uint4_t p0 = *(const uint4_t*)(ap1 + ko);
    uint4_t p1 = *(const uint4_t*)(ap1 + st32 + ko);
    uint4_t q0 = *(const uint4_t*)(ap3 + ko);
    uint4_t q1 = *(const uint4_t*)(ap3 + st32 + ko);

    short8_t af[4], b1f[4], b3f[4];
    #pragma unroll
    for (int s = 0; s < 4; ++s) {
      const int kof = s * 16 + lh * 8;
      af[s]  = *(const short8_t*)&As[cur][(wm * 32 + l31) * LDA + kof];
      b1f[s] = *(const short8_t*)&B1s[cur][(wn * 32 + l31) * LDA + kof];
      b3f[s] = *(const short8_t*)&B3s[cur][(wn * 32 + l31) * LDA + kof];
    }
    #pragma unroll
    for (int s = 0; s < 4; ++s) {
      acc1 = __builtin_amdgcn_mfma_f32_32x32x16_bf16(af[s], b1f[s], acc1, 0, 0, 0);
      acc3 = __builtin_amdgcn_mfma_f32_32x32x16_bf16(af[s], b3f[s], acc3, 0, 0, 0);
    }
    uint4_t a0 = {pkbf(v0[0] * sc0, v0[1] * sc0), pkbf(v0[2] * sc0, v0[3] * sc0),
                  pkbf(v1[0] * sc0, v1[1] * sc0), pkbf(v1[2] * sc0, v1[3] * sc0)};
    uint4_t a1 = {pkbf(w0[0] * sc1, w0[1] * sc1), pkbf(w0[2] * sc1, w0[3] * sc1),
                  pkbf(w1v[0] * sc1, w1v[1] * sc1), pkbf(w1v[2] * sc1, w1v[3] * sc1)};
    *(uint4_t*)&As[nxt][sr * LDA + su]         = a0;
    *(uint4_t*)&As[nxt][(sr + 32) * LDA + su]  = a1;
    *(uint4_t*)&B1s[nxt][sr * LDA + su]        = p0;
    *(uint4_t*)&B1s[nxt][(sr + 32) * LDA + su] = p1;
    *(uint4_t*)&B3s[nxt][sr * LDA + su]        = q0;
    *(uint4_t*)&B3s[nxt][(sr + 32) * LDA + su] = q1;
  }
  __syncthreads();                             // last tile in buf 1
  {
    short8_t af[4], b1f[4], b3f[4];
    #pragma unroll
    for (int s = 0; s < 4; ++s) {
      const int kof = s * 16 + lh * 8;
      af[s]  = *(const short8_t*)&As[1][(wm * 32 + l31) * LDA + kof];
      b1f[s] = *(const short8_t*)&B1s[1][(wn * 32 + l31) * LDA + kof];
      b3f[s] = *(const short8_t*)&B3s[1][(wn * 32 + l31) * LDA + kof];
    }
    #pragma unroll
    for (int s = 0; s < 4; ++s) {
      acc1 = __builtin_amdgcn_mfma_f32_32x32x16_bf16(af[s], b1f[s], acc1, 0, 0, 0);
      acc3 = __builtin_amdgcn_mfma_f32_32x32x16_bf16(af[s], b3f[s], acc3, 0, 0, 0);
    }
  }

  {                                            // epilogue: silu(c1)*c3 -> h
    const int col = n0 + wn * 32 + l31;
    #pragma unroll
    for (int r = 0; r < 16; ++r) {
      int mrow = (r & 3) + 8 * (r >> 2) + 4 * lh;
      int grow = row0 + wm * 32 + mrow;
      float c1 = acc1[r], c3 = acc3[r];
      float sig = 1.f / (1.f + __expf(-c1));
      h[(size_t)grow * H_DIM + col] = f2bf(c1 * sig * c3);
    }
  }
}

// -- gemm2 (fused combine): out[tok] += h @ w2t[e]; block 64m x 128n --------
// wave 32m x 64n (2 n-frags), 32x32x16 MFMA.
__global__ __launch_bounds__(256, 2) void gemm2_kernel(
    const short* __restrict__ h, const short* __restrict__ w2t,
    const int* __restrict__ pair_tok, const int* __restrict__ meta,
    float* __restrict__ out) {
  __shared__ short As[2][64 * LDA];    // 18.4 KB
  __shared__ short Bs[2][128 * LDA];   // 36.9 KB -> 55.3 KB total
  const int mt = blockIdx.y;
  if (mt >= meta[0]) return;
  const int e    = meta[1 + mt];
  const int row0 = meta[81 + mt];
  const int n0   = blockIdx.x * 128;
  const int tid = threadIdx.x, lane = tid & 63, wid = tid >> 6;
  const int wm = wid >> 1, wn = wid & 1;        // 2x2 waves, each 32m x 64n
  const int l31 = lane & 31, lh = lane >> 5;
  const short* bsrc = w2t + (size_t)e * D_DIM * H_DIM;  // [1024 n][512 k]

  const int sr = tid >> 3, su = (tid & 7) * 8;
  const size_t st32 = (size_t)32 * H_DIM;
  const short* apA = h    + (size_t)(row0 + sr) * H_DIM + su;
  const short* apB = bsrc + (size_t)(n0 + sr) * H_DIM + su;

  f32x16 accA, accB;
  #pragma unroll
  for (int i = 0; i < 16; ++i) { accA[i] = 0.f; accB[i] = 0.f; }

  {                                            // prologue: stage tile 0
    uint4_t a0 = *(const uint4_t*)apA;
    uint4_t a1 = *(const uint4_t*)(apA + st32);
    uint4_t b0 = *(const uint4_t*)apB;
    uint4_t b1 = *(const uint4_t*)(apB + st32);
    uint4_t b2 = *(const uint4_t*)(apB + 2 * st32);
    uint4_t b3 = *(const uint4_t*)(apB + 3 * st32);
    *(uint4_t*)&As[0][sr * LDA + su]        = a0;
    *(uint4_t*)&As[0][(sr + 32) * LDA + su] = a1;
    *(uint4_t*)&Bs[0][sr * LDA + su]        = b0;
    *(uint4_t*)&Bs[0][(sr + 32) * LDA + su] = b1;
    *(uint4_t*)&Bs[0][(sr + 64) * LDA + su] = b2;
    *(uint4_t*)&Bs[0][(sr + 96) * LDA + su] = b3;
  }

  for (int t = 0; t < NK2 - 1; ++t) {
    __syncthreads();
    const int cur = t & 1, nxt = cur ^ 1;
    const int ko = (t + 1) * 64;
    uint4_t a0 = *(const uint4_t*)(apA + ko);
    uint4_t a1 = *(const uint4_t*)(apA + st32 + ko);
    uint4_t b0 = *(const uint4_t*)(apB + ko);
    uint4_t b1 = *(const uint4_t*)(apB + st32 + ko);
    uint4_t b2 = *(const uint4_t*)(apB + 2 * st32 + ko);
    uint4_t b3 = *(const uint4_t*)(apB + 3 * st32 + ko);

    short8_t af[4], bf0[4], bf1[4];
    #pragma unroll
    for (int s = 0; s < 4; ++s) {
      const int kof = s * 16 + lh * 8;
      af[s]  = *(const short8_t*)&As[cur][(wm * 32 + l31) * LDA + kof];
      bf0[s] = *(const short8_t*)&Bs[cur][(wn * 64 + l31) * LDA + kof];
      bf1[s] = *(const short8_t*)&Bs[cur][(wn * 64 + 32 + l31) * LDA + kof];
    }
    #pragma unroll
    for (int s = 0; s < 4; ++s) {
      accA = __builtin_amdgcn_mfma_f32_32x32x16_bf16(af[s], bf0[s], accA, 0, 0, 0);
      accB = __builtin_amdgcn_mfma_f32_32x32x16_bf16(af[s], bf1[s], accB, 0, 0, 0);
    }
    *(uint4_t*)&As[nxt][sr * LDA + su]        = a0;
    *(uint4_t*)&As[nxt][(sr + 32) * LDA + su] = a1;
    *(uint4_t*)&Bs[nxt][sr * LDA + su]        = b0;
    *(uint4_t*)&Bs[nxt][(sr + 32) * LDA + su] = b1;
    *(uint4_t*)&Bs[nxt][(sr + 64) * LDA + su] = b2;
    *(uint4_t*)&Bs[nxt][(sr + 96) * LDA + su] = b3;
  }
  __syncthreads();                             // last tile in buf 1
  {
    short8_t af[4], bf0[4], bf1[4];
    #pragma unroll
    for (int s = 0; s < 4; ++s) {
      const int kof = s * 16 + lh * 8;
      af[s]  = *(const short8_t*)&As[1][(wm * 32 + l31) * LDA + kof];
      bf0[s] = *(const short8_t*)&Bs[1][(wn * 64 + l31) * LDA + kof];
      bf1[s] = *(const short8_t*)&Bs[1][(wn * 64 + 32 + l31) * LDA + kof];
    }
    #pragma unroll
    for (int s = 0; s < 4; ++s) {
      accA = __builtin_amdgcn_mfma_f32_32x32x16_bf16(af[s], bf0[s], accA, 0, 0, 0);
      accB = __builtin_amdgcn_mfma_f32_32x32x16_bf16(af[s], bf1[s], accB, 0, 0, 0);
    }
  }

  // ---- epilogue: scatter-add into out[tok]; skip pad rows (tok < 0)
  {
    #pragma unroll
    for (int r = 0; r < 16; ++r) {
      int mrow = (r & 3) + 8 * (r >> 2) + 4 * lh;
      int grow = row0 + wm * 32 + mrow;
      int tok = pair_tok[grow];
      if (tok < 0) continue;
      float* orow = out + (size_t)tok * D_DIM;
      atomicAdd(orow + n0 + wn * 64 + l31, accA[r]);
      atomicAdd(orow + n0 + wn * 64 + 32 + l31, accB[r]);
    }
  }
}

extern "C" void kernel_launch(void* const* d_in, const int* in_sizes, int n_in,
                              void* d_out, int out_size, void* d_ws, size_t ws_size,
                              hipStream_t stream) {
  const float* x  = (const float*)d_in[0];   // [2,512,1024]
  const float* gw = (const float*)d_in[1];   // [1024,8]
  const float* w1 = (const float*)d_in[2];   // [8,1024,512] gate
  const float* w2 = (const float*)d_in[3];   // [8,512,1024] down
  const float* w3 = (const float*)d_in[4];   // [8,1024,512] up
  float* out = (float*)d_out;

  char* ws = (char*)d_ws;
  int*   idx2    = (int*)  (ws);                       // 8KB
  float* scale2  = (float*)(ws + 8192);                // 8KB
  int*   ptok    = (int*)  (ws + 16384);               // 10KB (16KB slot)
  float* pscale  = (float*)(ws + 32768);               // 10KB (16KB slot)
  int*   meta    = (int*)  (ws + 49152);               // 640B (16KB slot)
  short* h       = (short*)(ws + (1u << 20));          // 2.62 MB
  short* w13t    = (short*)(ws + (4u << 20));          // 16.8 MB
  short* w2t     = (short*)(ws + (21u << 20));         // 8.4 MB

  prep_kernel<<<dim3(3584), dim3(256), 0, stream>>>(
      w1, w3, w2, x, gw, w13t, w2t, idx2, scale2, out);
  scan_kernel<<<dim3(1), dim3(256), 0, stream>>>(idx2, scale2, ptok, pscale, meta);
  gemm1_kernel<<<dim3(H_DIM / 64, MAX_MT), dim3(256), 0, stream>>>(
      x, w13t, ptok, pscale, meta, h);
  gemm2_kernel<<<dim3(D_DIM / 128, MAX_MT), dim3(256), 0, stream>>>(
      h, w2t, ptok, meta, out);
}

// Round 6
// 147.686 us; speedup vs baseline: 1.0341x; 1.0341x over previous
//
#include <hip/hip_runtime.h>
#include <hip/hip_bf16.h>
#include <cstddef>

#define T_TOK 1024
#define D_DIM 1024
#define H_DIM 512
#define E_EXP 8
#define MAX_MT 40           // 64-row m-tiles: sum ceil(cnt_e/64) <= 39
#define LDA 72              // shorts per LDS row: 64 data + 8 pad (144B, 16B-aligned)
#define NK1 16              // gemm1 K-steps: 1024/64
#define NK2 8               // gemm2 K-steps: 512/64

typedef __attribute__((ext_vector_type(4)))  float    float4_t;
typedef __attribute__((ext_vector_type(16))) float    f32x16;
typedef __attribute__((ext_vector_type(8)))  short    short8_t;
typedef __attribute__((ext_vector_type(4)))  unsigned uint4_t;

__device__ __forceinline__ short f2bf(float f) {
  union { float f; unsigned u; } v; v.f = f;
  unsigned u = v.u;
  u += 0x7FFFu + ((u >> 16) & 1u);
  return (short)(u >> 16);
}

// packed fp32x2 -> bf16x2; low short = a, high = b
__device__ __forceinline__ unsigned pkbf(float a, float b) {
  union { __hip_bfloat162 h; unsigned u; } v;
  v.h = __float22bfloat162_rn(make_float2(a, b));
  return v.u;
}

// ---- prep: flat 1-D grid of 3584 real work units (no idle blocks):
//   u <  2048 : w1/w3 transpose 64x64 tiles (16 z * 16 kt * 8 nt)
//   u <  3072 : w2 transpose tiles (8 e * 8 kt * 16 nt)
//   u <  3328 : router, 4 tokens per unit
//   u <  3584 : out-zero, 16 KB per unit
__global__ __launch_bounds__(256) void prep_kernel(
    const float* __restrict__ w1, const float* __restrict__ w3,
    const float* __restrict__ w2, const float* __restrict__ x,
    const float* __restrict__ gw, short* __restrict__ w13t,
    short* __restrict__ w2t, int* __restrict__ idx2,
    float* __restrict__ scale2, float* __restrict__ out) {
  __shared__ float tile[64][69];           // odd stride keeps transpose <=2-way
  const int u = blockIdx.x;
  const int tid = threadIdx.x;

  if (u < 3072) {
    const float* src; short* dst; int N, ldd, row_off, k0, n0;
    if (u < 2048) {
      int z = u >> 7, rem = u & 127;
      int kt = rem & 15, nt = rem >> 4;    // 16 kt x 8 nt
      int which = z >> 3, e = z & 7;
      src = (which ? w3 : w1) + (size_t)e * D_DIM * H_DIM;
      dst = w13t + (size_t)e * D_DIM * (2 * H_DIM);
      N = H_DIM; ldd = D_DIM; row_off = which ? H_DIM : 0;
      k0 = kt * 64; n0 = nt * 64;
    } else {
      int v = u - 2048;
      int e = v >> 7, rem = v & 127;
      int kt = rem & 7, nt = rem >> 3;     // 8 kt x 16 nt
      src = w2 + (size_t)e * H_DIM * D_DIM;
      dst = w2t + (size_t)e * D_DIM * H_DIM;
      N = D_DIM; ldd = H_DIM; row_off = 0;
      k0 = kt * 64; n0 = nt * 64;
    }
    const int kr = tid >> 4, nc = (tid & 15) * 4;
    #pragma unroll
    for (int p = 0; p < 4; ++p) {
      int k = p * 16 + kr;
      float4_t v = *(const float4_t*)(src + (size_t)(k0 + k) * N + n0 + nc);
      tile[k][nc]     = v[0];
      tile[k][nc + 1] = v[1];
      tile[k][nc + 2] = v[2];
      tile[k][nc + 3] = v[3];
    }
    __syncthreads();
    const int r8 = tid >> 3, c8 = tid & 7;
    #pragma unroll
    for (int p = 0; p < 2; ++p) {
      int row = p * 32 + r8;
      uint4_t uu;
      #pragma unroll
      for (int jj = 0; jj < 4; ++jj)
        uu[jj] = pkbf(tile[c8 * 8 + 2 * jj][row], tile[c8 * 8 + 2 * jj + 1][row]);
      *(uint4_t*)(dst + (size_t)(row_off + n0 + row) * ldd + k0 + c8 * 8) = uu;
    }
    return;
  }

  if (u >= 3328) {                          // out zero: 256 units x 16KB
    int v = u - 3328;
    float4_t z4 = {0.f, 0.f, 0.f, 0.f};
    float4_t* o = (float4_t*)(out + (size_t)v * 4096);
    #pragma unroll
    for (int i = 0; i < 4; ++i) o[i * 256 + tid] = z4;
    return;
  }

  // router: 4 tokens per unit (one wave each)
  const int wid  = tid >> 6;
  const int lane = tid & 63;
  const int t = (u - 3072) * 4 + wid;
  const float* xr = x + (size_t)t * D_DIM;
  float acc[E_EXP];
  #pragma unroll
  for (int e = 0; e < E_EXP; ++e) acc[e] = 0.f;
  for (int d = lane; d < D_DIM; d += 64) {
    float xv = xr[d];
    float4_t g0 = *(const float4_t*)(gw + d * E_EXP);
    float4_t g1 = *(const float4_t*)(gw + d * E_EXP + 4);
    acc[0] += xv * g0[0]; acc[1] += xv * g0[1];
    acc[2] += xv * g0[2]; acc[3] += xv * g0[3];
    acc[4] += xv * g1[0]; acc[5] += xv * g1[1];
    acc[6] += xv * g1[2]; acc[7] += xv * g1[3];
  }
  #pragma unroll
  for (int off = 32; off >= 1; off >>= 1) {
    #pragma unroll
    for (int e = 0; e < E_EXP; ++e) acc[e] += __shfl_down(acc[e], off, 64);
  }
  if (lane == 0) {
    float m = acc[0];
    #pragma unroll
    for (int e = 1; e < E_EXP; ++e) m = fmaxf(m, acc[e]);
    float p[E_EXP]; float s = 0.f;
    #pragma unroll
    for (int e = 0; e < E_EXP; ++e) { p[e] = __expf(acc[e] - m); s += p[e]; }
    float inv = 1.f / s;
    #pragma unroll
    for (int e = 0; e < E_EXP; ++e) p[e] *= inv;
    int i1 = 0;
    #pragma unroll
    for (int e = 1; e < E_EXP; ++e) if (p[e] > p[i1]) i1 = e;  // jax low-index tiebreak
    int i2 = (i1 == 0) ? 1 : 0;
    #pragma unroll
    for (int e = 0; e < E_EXP; ++e) {
      if (e == i1 || e == i2) continue;
      if (p[e] > p[i2]) i2 = e;
    }
    idx2[2 * t]     = i1;  scale2[2 * t]     = p[i1];
    idx2[2 * t + 1] = i2;  scale2[2 * t + 1] = p[i2];
  }
}

// ---- per-block routing prologue (replaces the 44us single-block scan):
// every gemm block recomputes, from idx2 (8KB, L2-hot), the expert counts,
// the 64-aligned tile decomposition, and its own 64-row (tok, scale) window
// via ballot rank-select. Deterministic and identical across gemm1/gemm2.
// Returns false if this mt has no tile. Fills ltok/lsc (pad rows: -1 / 0).
__device__ __forceinline__ bool route_block(
    const int* __restrict__ idx2, const float* __restrict__ scale2,
    int mt, int tid, int (&wcnt)[32][E_EXP], int (&woff)[32][E_EXP],
    int (&scnt)[E_EXP], int (&ltok)[64], float (&lsc)[64],
    int& e_sel, int& grow0) {
  const int lane = tid & 63, wv4 = tid >> 6;
  const unsigned long long lt = (1ull << lane) - 1ull;

  int ex[8];
  #pragma unroll
  for (int c = 0; c < 8; ++c) ex[c] = idx2[c * 256 + wv4 * 64 + lane];

  #pragma unroll
  for (int c = 0; c < 8; ++c) {
    #pragma unroll
    for (int e = 0; e < E_EXP; ++e) {
      unsigned long long m = __ballot(ex[c] == e);
      if (lane == 0) wcnt[c * 4 + wv4][e] = (int)__popcll(m);
    }
  }
  if (tid < 64) { ltok[tid] = -1; lsc[tid] = 0.f; }
  __syncthreads();
  {
    int g = tid >> 3, e = tid & 7;           // 256 threads = 32 groups x 8 experts
    int pre = 0;
    for (int gg = 0; gg < g; ++gg) pre += wcnt[gg][e];
    woff[g][e] = pre;                        // bucket-local prefix before group g
    if (g == 31) scnt[e] = pre + wcnt[31][e];
  }
  __syncthreads();
  int row0 = -1;
  {
    int accT = 0, base = 0;
    e_sel = -1; grow0 = -1;
    #pragma unroll
    for (int e = 0; e < E_EXP; ++e) {
      int ce = scnt[e];
      int nt = (ce + 63) >> 6;
      if (mt >= accT && mt < accT + nt) {
        e_sel = e; row0 = (mt - accT) * 64; grow0 = base + row0;
      }
      accT += nt; base += nt * 64;
    }
    if (mt >= accT) return false;            // uniform per block
  }
  #pragma unroll
  for (int c = 0; c < 8; ++c) {
    int p = c * 256 + wv4 * 64 + lane;       // pair index = 2*t + s
    int myE = ex[c];
    unsigned long long msel = 0;
    #pragma unroll
    for (int e = 0; e < E_EXP; ++e) {
      unsigned long long m = __ballot(myE == e);
      if (myE == e) msel = m;
    }
    int r = woff[c * 4 + wv4][myE] + (int)__popcll(msel & lt);
    if (myE == e_sel && r >= row0 && r < row0 + 64) {
      ltok[r - row0] = p >> 1;
      lsc[r - row0]  = scale2[p];
    }
  }
  __syncthreads();
  return true;
}

// ------- gemm1: h = silu((s*x)@w1e) * ((s*x)@w3e); block 64m x 64n ---------
// 32x32x16 MFMA; A/B frag row=lane&31, k=(lane>>5)*8+j; C/D col=lane&31,
// row=(reg&3)+8*(reg>>2)+4*(lane>>5)  [m74/m101 verified].
__global__ __launch_bounds__(256, 2) void gemm1_kernel(
    const float* __restrict__ x, const short* __restrict__ w13t,
    const int* __restrict__ idx2, const float* __restrict__ scale2,
    short* __restrict__ h) {
  __shared__ short As[2][64 * LDA];    // 18.4 KB
  __shared__ short B1s[2][64 * LDA];   // 18.4 KB
  __shared__ short B3s[2][64 * LDA];   // 18.4 KB
  __shared__ int wcnt[32][E_EXP], woff[32][E_EXP], scnt[E_EXP], ltok[64];
  __shared__ float lsc[64];            // total ~57.9 KB < 64 KB
  const int mt = blockIdx.y;
  const int tid = threadIdx.x, lane = tid & 63, wid = tid >> 6;

  int e_sel, grow0;
  if (!route_block(idx2, scale2, mt, tid, wcnt, woff, scnt, ltok, lsc,
                   e_sel, grow0)) return;

  const int n0   = blockIdx.x * 64;
  const int wm = wid >> 1, wn = wid & 1;        // 2x2 waves, each 32m x 32n
  const int l31 = lane & 31, lh = lane >> 5;
  const short* bsrc = w13t + (size_t)e_sel * D_DIM * (2 * H_DIM);

  const int sr = tid >> 3, su = (tid & 7) * 8;
  const size_t st32 = (size_t)32 * D_DIM;
  const int   tok0 = ltok[sr];
  const int   tok1 = ltok[sr + 32];
  const float sc0  = lsc[sr];                   // 0 for pad rows -> zeros
  const float sc1  = lsc[sr + 32];
  const float* xr0 = x + (size_t)(tok0 < 0 ? 0 : tok0) * D_DIM + su;
  const float* xr1 = x + (size_t)(tok1 < 0 ? 0 : tok1) * D_DIM + su;
  const short* ap1 = bsrc + (size_t)(n0 + sr) * D_DIM + su;
  const short* ap3 = bsrc + (size_t)(H_DIM + n0 + sr) * D_DIM + su;

  f32x16 acc1, acc3;
  #pragma unroll
  for (int i = 0; i < 16; ++i) { acc1[i] = 0.f; acc3[i] = 0.f; }

  {                                            // prologue: stage tile 0
    float4_t v0 = *(const float4_t*)(xr0);
    float4_t v1 = *(const float4_t*)(xr0 + 4);
    float4_t w0 = *(const float4_t*)(xr1);
    float4_t w1v = *(const float4_t*)(xr1 + 4);
    uint4_t a0 = {pkbf(v0[0] * sc0, v0[1] * sc0), pkbf(v0[2] * sc0, v0[3] * sc0),
                  pkbf(v1[0] * sc0, v1[1] * sc0), pkbf(v1[2] * sc0, v1[3] * sc0)};
    uint4_t a1 = {pkbf(w0[0] * sc1, w0[1] * sc1), pkbf(w0[2] * sc1, w0[3] * sc1),
                  pkbf(w1v[0] * sc1, w1v[1] * sc1), pkbf(w1v[2] * sc1, w1v[3] * sc1)};
    uint4_t p0 = *(const uint4_t*)ap1;
    uint4_t p1 = *(const uint4_t*)(ap1 + st32);
    uint4_t q0 = *(const uint4_t*)ap3;
    uint4_t q1 = *(const uint4_t*)(ap3 + st32);
    *(uint4_t*)&As[0][sr * LDA + su]         = a0;
    *(uint4_t*)&As[0][(sr + 32) * LDA + su]  = a1;
    *(uint4_t*)&B1s[0][sr * LDA + su]        = p0;
    *(uint4_t*)&B1s[0][(sr + 32) * LDA + su] = p1;
    *(uint4_t*)&B3s[0][sr * LDA + su]        = q0;
    *(uint4_t*)&B3s[0][(sr + 32) * LDA + su] = q1;
  }

  for (int t = 0; t < NK1 - 1; ++t) {
    __syncthreads();
    const int cur = t & 1, nxt = cur ^ 1;
    const int ko = (t + 1) * 64;
    float4_t v0 = *(const float4_t*)(xr0 + ko);
    float4_t v1 = *(const float4_t*)(xr0 + ko + 4);
    float4_t w0 = *(const float4_t*)(xr1 + ko);
    float4_t w1v = *(const float4_t*)(xr1 + ko + 4);
    uint4_t p0 = *(const uint4_t*)(ap1 + ko);
    uint4_t p1 = *(const uint4_t*)(ap1 + st32 + ko);
    uint4_t q0 = *(const uint4_t*)(ap3 + ko);
    uint4_t q1 = *(const uint4_t*)(ap3 + st32 + ko);

    short8_t af[4], b1f[4], b3f[4];
    #pragma unroll
    for (int s = 0; s < 4; ++s) {
      const int kof = s * 16 + lh * 8;
      af[s]  = *(const short8_t*)&As[cur][(wm * 32 + l31) * LDA + kof];
      b1f[s] = *(const short8_t*)&B1s[cur][(wn * 32 + l31) * LDA + kof];
      b3f[s] = *(const short8_t*)&B3s[cur][(wn * 32 + l31) * LDA + kof];
    }
    #pragma unroll
    for (int s = 0; s < 4; ++s) {
      acc1 = __builtin_amdgcn_mfma_f32_32x32x16_bf16(af[s], b1f[s], acc1, 0, 0, 0);
      acc3 = __builtin_amdgcn_mfma_f32_32x32x16_bf16(af[s], b3f[s], acc3, 0, 0, 0);
    }
    uint4_t a0 = {pkbf(v0[0] * sc0, v0[1] * sc0), pkbf(v0[2] * sc0, v0[3] * sc0),
                  pkbf(v1[0] * sc0, v1[1] * sc0), pkbf(v1[2] * sc0, v1[3] * sc0)};
    uint4_t a1 = {pkbf(w0[0] * sc1, w0[1] * sc1), pkbf(w0[2] * sc1, w0[3] * sc1),
                  pkbf(w1v[0] * sc1, w1v[1] * sc1), pkbf(w1v[2] * sc1, w1v[3] * sc1)};
    *(uint4_t*)&As[nxt][sr * LDA + su]         = a0;
    *(uint4_t*)&As[nxt][(sr + 32) * LDA + su]  = a1;
    *(uint4_t*)&B1s[nxt][sr * LDA + su]        = p0;
    *(uint4_t*)&B1s[nxt][(sr + 32) * LDA + su] = p1;
    *(uint4_t*)&B3s[nxt][sr * LDA + su]        = q0;
    *(uint4_t*)&B3s[nxt][(sr + 32) * LDA + su] = q1;
  }
  __syncthreads();                             // last tile in buf 1
  {
    short8_t af[4], b1f[4], b3f[4];
    #pragma unroll
    for (int s = 0; s < 4; ++s) {
      const int kof = s * 16 + lh * 8;
      af[s]  = *(const short8_t*)&As[1][(wm * 32 + l31) * LDA + kof];
      b1f[s] = *(const short8_t*)&B1s[1][(wn * 32 + l31) * LDA + kof];
      b3f[s] = *(const short8_t*)&B3s[1][(wn * 32 + l31) * LDA + kof];
    }
    #pragma unroll
    for (int s = 0; s < 4; ++s) {
      acc1 = __builtin_amdgcn_mfma_f32_32x32x16_bf16(af[s], b1f[s], acc1, 0, 0, 0);
      acc3 = __builtin_amdgcn_mfma_f32_32x32x16_bf16(af[s], b3f[s], acc3, 0, 0, 0);
    }
  }

  {                                            // epilogue: silu(c1)*c3 -> h
    const int col = n0 + wn * 32 + l31;
    #pragma unroll
    for (int r = 0; r < 16; ++r) {
      int mrow = (r & 3) + 8 * (r >> 2) + 4 * lh;
      int grow = grow0 + wm * 32 + mrow;
      float c1 = acc1[r], c3 = acc3[r];
      float sig = 1.f / (1.f + __expf(-c1));
      h[(size_t)grow * H_DIM + col] = f2bf(c1 * sig * c3);
    }
  }
}

// -- gemm2 (fused combine): out[tok] += h @ w2t[e]; block 64m x 128n --------
// wave 32m x 64n (2 n-frags), 32x32x16 MFMA.
__global__ __launch_bounds__(256, 2) void gemm2_kernel(
    const short* __restrict__ h, const short* __restrict__ w2t,
    const int* __restrict__ idx2, const float* __restrict__ scale2,
    float* __restrict__ out) {
  __shared__ short As[2][64 * LDA];    // 18.4 KB
  __shared__ short Bs[2][128 * LDA];   // 36.9 KB
  __shared__ int wcnt[32][E_EXP], woff[32][E_EXP], scnt[E_EXP], ltok[64];
  __shared__ float lsc[64];            // total ~57.9 KB < 64 KB
  const int mt = blockIdx.y;
  const int tid = threadIdx.x, lane = tid & 63, wid = tid >> 6;

  int e_sel, grow0;
  if (!route_block(idx2, scale2, mt, tid, wcnt, woff, scnt, ltok, lsc,
                   e_sel, grow0)) return;

  const int n0   = blockIdx.x * 128;
  const int wm = wid >> 1, wn = wid & 1;        // 2x2 waves, each 32m x 64n
  const int l31 = lane & 31, lh = lane >> 5;
  const short* bsrc = w2t + (size_t)e_sel * D_DIM * H_DIM;  // [1024 n][512 k]

  const int sr = tid >> 3, su = (tid & 7) * 8;
  const size_t st32 = (size_t)32 * H_DIM;
  const short* apA = h    + (size_t)(grow0 + sr) * H_DIM + su;
  const short* apB = bsrc + (size_t)(n0 + sr) * H_DIM + su;

  f32x16 accA, accB;
  #pragma unroll
  for (int i = 0; i < 16; ++i) { accA[i] = 0.f; accB[i] = 0.f; }

  {                                            // prologue: stage tile 0
    uint4_t a0 = *(const uint4_t*)apA;
    uint4_t a1 = *(const uint4_t*)(apA + st32);
    uint4_t b0 = *(const uint4_t*)apB;
    uint4_t b1 = *(const uint4_t*)(apB + st32);
    uint4_t b2 = *(const uint4_t*)(apB + 2 * st32);
    uint4_t b3 = *(const uint4_t*)(apB + 3 * st32);
    *(uint4_t*)&As[0][sr * LDA + su]        = a0;
    *(uint4_t*)&As[0][(sr + 32) * LDA + su] = a1;
    *(uint4_t*)&Bs[0][sr * LDA + su]        = b0;
    *(uint4_t*)&Bs[0][(sr + 32) * LDA + su] = b1;
    *(uint4_t*)&Bs[0][(sr + 64) * LDA + su] = b2;
    *(uint4_t*)&Bs[0][(sr + 96) * LDA + su] = b3;
  }

  for (int t = 0; t < NK2 - 1; ++t) {
    __syncthreads();
    const int cur = t & 1, nxt = cur ^ 1;
    const int ko = (t + 1) * 64;
    uint4_t a0 = *(const uint4_t*)(apA + ko);
    uint4_t a1 = *(const uint4_t*)(apA + st32 + ko);
    uint4_t b0 = *(const uint4_t*)(apB + ko);
    uint4_t b1 = *(const uint4_t*)(apB + st32 + ko);
    uint4_t b2 = *(const uint4_t*)(apB + 2 * st32 + ko);
    uint4_t b3 = *(const uint4_t*)(apB + 3 * st32 + ko);

    short8_t af[4], bf0[4], bf1[4];
    #pragma unroll
    for (int s = 0; s < 4; ++s) {
      const int kof = s * 16 + lh * 8;
      af[s]  = *(const short8_t*)&As[cur][(wm * 32 + l31) * LDA + kof];
      bf0[s] = *(const short8_t*)&Bs[cur][(wn * 64 + l31) * LDA + kof];
      bf1[s] = *(const short8_t*)&Bs[cur][(wn * 64 + 32 + l31) * LDA + kof];
    }
    #pragma unroll
    for (int s = 0; s < 4; ++s) {
      accA = __builtin_amdgcn_mfma_f32_32x32x16_bf16(af[s], bf0[s], accA, 0, 0, 0);
      accB = __builtin_amdgcn_mfma_f32_32x32x16_bf16(af[s], bf1[s], accB, 0, 0, 0);
    }
    *(uint4_t*)&As[nxt][sr * LDA + su]        = a0;
    *(uint4_t*)&As[nxt][(sr + 32) * LDA + su] = a1;
    *(uint4_t*)&Bs[nxt][sr * LDA + su]        = b0;
    *(uint4_t*)&Bs[nxt][(sr + 32) * LDA + su] = b1;
    *(uint4_t*)&Bs[nxt][(sr + 64) * LDA + su] = b2;
    *(uint4_t*)&Bs[nxt][(sr + 96) * LDA + su] = b3;
  }
  __syncthreads();                             // last tile in buf 1
  {
    short8_t af[4], bf0[4], bf1[4];
    #pragma unroll
    for (int s = 0; s < 4; ++s) {
      const int kof = s * 16 + lh * 8;
      af[s]  = *(const short8_t*)&As[1][(wm * 32 + l31) * LDA + kof];
      bf0[s] = *(const short8_t*)&Bs[1][(wn * 64 + l31) * LDA + kof];
      bf1[s] = *(const short8_t*)&Bs[1][(wn * 64 + 32 + l31) * LDA + kof];
    }
    #pragma unroll
    for (int s = 0; s < 4; ++s) {
      accA = __builtin_amdgcn_mfma_f32_32x32x16_bf16(af[s], bf0[s], accA, 0, 0, 0);
      accB = __builtin_amdgcn_mfma_f32_32x32x16_bf16(af[s], bf1[s], accB, 0, 0, 0);
    }
  }

  // ---- epilogue: scatter-add into out[tok]; skip pad rows (tok < 0)
  {
    #pragma unroll
    for (int r = 0; r < 16; ++r) {
      int mrow = (r & 3) + 8 * (r >> 2) + 4 * lh;
      int tok = ltok[wm * 32 + mrow];
      if (tok < 0) continue;
      float* orow = out + (size_t)tok * D_DIM;
      atomicAdd(orow + n0 + wn * 64 + l31, accA[r]);
      atomicAdd(orow + n0 + wn * 64 + 32 + l31, accB[r]);
    }
  }
}

extern "C" void kernel_launch(void* const* d_in, const int* in_sizes, int n_in,
                              void* d_out, int out_size, void* d_ws, size_t ws_size,
                              hipStream_t stream) {
  const float* x  = (const float*)d_in[0];   // [2,512,1024]
  const float* gw = (const float*)d_in[1];   // [1024,8]
  const float* w1 = (const float*)d_in[2];   // [8,1024,512] gate
  const float* w2 = (const float*)d_in[3];   // [8,512,1024] down
  const float* w3 = (const float*)d_in[4];   // [8,1024,512] up
  float* out = (float*)d_out;

  char* ws = (char*)d_ws;
  int*   idx2    = (int*)  (ws);                       // 8KB
  float* scale2  = (float*)(ws + 8192);                // 8KB
  short* h       = (short*)(ws + (1u << 20));          // 2.62 MB
  short* w13t    = (short*)(ws + (4u << 20));          // 16.8 MB
  short* w2t     = (short*)(ws + (21u << 20));         // 8.4 MB

  prep_kernel<<<dim3(3584), dim3(256), 0, stream>>>(
      w1, w3, w2, x, gw, w13t, w2t, idx2, scale2, out);
  gemm1_kernel<<<dim3(H_DIM / 64, MAX_MT), dim3(256), 0, stream>>>(
      x, w13t, idx2, scale2, h);
  gemm2_kernel<<<dim3(D_DIM / 128, MAX_MT), dim3(256), 0, stream>>>(
      h, w2t, idx2, scale2, out);
}